// Round 2
// baseline (473.838 us; speedup 1.0000x reference)
//
#include <hip/hip_runtime.h>

typedef __attribute__((ext_vector_type(8))) short  short8;   // 8 x bf16 bits = 4 VGPR
typedef __attribute__((ext_vector_type(4))) float  float4v;
typedef __attribute__((ext_vector_type(4))) int    int4v;

#define E_TILE 64
#define LDH    136   // sH: 128 + 8 bf16 pad
#define PGRID  768   // persistent grid: 3 blocks/CU x 256 CU

// lgkm-only barrier: LDS ops drained, global_load_lds (vmcnt) stays in flight
#define BAR_LGKM asm volatile("s_waitcnt lgkmcnt(0)\n\ts_barrier" ::: "memory")

// fp32 -> bf16 bits, round-to-nearest-even (weight prologue only)
__device__ __forceinline__ short f2bf(float f) {
    union { float f; unsigned u; } v; v.f = f;
    unsigned r = (v.u + 0x7FFFu + ((v.u >> 16) & 1u)) >> 16;
    return (short)r;
}

// ---- pre-pass: x fp32 -> bf16 (once; 25.6MB read, 12.8MB write) ----
__global__ __launch_bounds__(256)
void cvt_x_kernel(const float* __restrict__ x, short* __restrict__ x16, long n8) {
    long i = (long)blockIdx.x * 256 + threadIdx.x;   // units of 8 floats
    if (i >= n8) return;
    const float4v* p = (const float4v*)(x + i * 8);
    float4v a = p[0], b = p[1];
    unsigned r0, r1, r2, r3;
    asm("v_cvt_pk_bf16_f32 %0, %1, %2" : "=v"(r0) : "v"(a.x), "v"(a.y));
    asm("v_cvt_pk_bf16_f32 %0, %1, %2" : "=v"(r1) : "v"(a.z), "v"(a.w));
    asm("v_cvt_pk_bf16_f32 %0, %1, %2" : "=v"(r2) : "v"(b.x), "v"(b.y));
    asm("v_cvt_pk_bf16_f32 %0, %1, %2" : "=v"(r3) : "v"(b.z), "v"(b.w));
    int4v o; o.x = (int)r0; o.y = (int)r1; o.z = (int)r2; o.w = (int)r3;
    *(int4v*)(x16 + i * 8) = o;
}

__global__ __launch_bounds__(256, 3)
void edge_mlp_kernel(const short* __restrict__ x16,
                     const int*   __restrict__ ei,
                     const float* __restrict__ W1,
                     const float* __restrict__ b1,
                     const float* __restrict__ W2,
                     const float* __restrict__ b2,
                     float*       __restrict__ out,
                     int E, int nTiles) {
    // sA: 64 edges x 256 bf16, LINEAR (global_load_lds dest), XOR-swizzled content
    __shared__ short sA[E_TILE * 256];        // 32768 B
    __shared__ short sH[E_TILE * LDH];        // 17408 B (reused as fp32 slabs in epilogue)
    __shared__ int   sIdx[2][2 * E_TILE];     // 1024 B   -> total 51200 B -> 3 blocks/CU

    const int tid  = threadIdx.x;
    const int wave = tid >> 6;
    const int lane = tid & 63;
    const int quad = lane >> 4;
    const int l16  = lane & 15;
    const int nBase = wave * 32;              // wave owns N-slice [nBase, nBase+32)
    const int G = gridDim.x;

    // ---- persistent weight preload (once per block) ----
    short8 bw1[8][2];   // K1=256: 8 k-steps; 2 n-tiles
    short8 bw2[4][2];   // K2=128: 4 k-steps
    #pragma unroll
    for (int kt = 0; kt < 8; ++kt)
        #pragma unroll
        for (int nt = 0; nt < 2; ++nt) {
            short8 f;
            #pragma unroll
            for (int j = 0; j < 8; ++j)
                f[j] = f2bf(W1[(kt * 32 + quad * 8 + j) * 128 + nBase + nt * 16 + l16]);
            bw1[kt][nt] = f;
        }
    #pragma unroll
    for (int kt = 0; kt < 4; ++kt)
        #pragma unroll
        for (int nt = 0; nt < 2; ++nt) {
            short8 f;
            #pragma unroll
            for (int j = 0; j < 8; ++j)
                f[j] = f2bf(W2[(kt * 32 + quad * 8 + j) * 128 + nBase + nt * 16 + l16]);
            bw2[kt][nt] = f;
        }
    float b1v[2], b2v[2];
    #pragma unroll
    for (int nt = 0; nt < 2; ++nt) {
        b1v[nt] = b1[nBase + nt * 16 + l16];
        b2v[nt] = b2[nBase + nt * 16 + l16];
    }

    auto stageIdx = [&](int b, int t) {
        if (tid < E_TILE) {
            int s = 0, d = 0;
            if (t < nTiles) {
                long eg = (long)t * E_TILE + tid;
                if (eg < (long)E) { s = ei[eg]; d = ei[(long)E + eg]; }
            }
            sIdx[b][tid] = s;
            sIdx[b][E_TILE + tid] = d;
        }
    };

    // gather via global_load_lds: 2048 x 16B chunks, linear LDS dest,
    // XOR-swizzled global source (chunk c = cl ^ (row&7))
    auto gather = [&](int b) {
        #pragma unroll
        for (int r = 0; r < 8; ++r) {
            int lin = tid + 256 * r;              // 16B-chunk id in [0,2048)
            int row = lin >> 5;                   // edge row (32 chunks/row)
            int cl  = lin & 31;                   // linear chunk in LDS
            int c   = cl ^ (row & 7);             // logical chunk (swizzle)
            int node = (c < 16) ? sIdx[b][row] : sIdx[b][E_TILE + row];
            const short* gp = x16 + (long)node * 128 + (c & 15) * 8;
            __builtin_amdgcn_global_load_lds(
                (const __attribute__((address_space(1))) void*)gp,
                (__attribute__((address_space(3))) void*)&sA[lin * 8],
                16, 0, 0);
        }
    };

    // ---- prologue ----
    const int t0 = blockIdx.x;
    if (t0 >= nTiles) return;
    stageIdx(0, t0);
    __syncthreads();                 // sIdx[0] visible
    gather(0);
    stageIdx(1, t0 + G);
    __syncthreads();                 // drains vmcnt: sA(t0) + sIdx[1] ready

    int p = 1;                       // sIdx[p] holds indices for tile t+G
    for (int t = t0; t < nTiles; t += G) {
        const long eBase = (long)t * E_TILE;

        // ---- GEMM1: H = relu(A @ W1 + b1); A read with matching XOR-swizzle ----
        float4v acc[4][2];
        #pragma unroll
        for (int mt = 0; mt < 4; ++mt)
            #pragma unroll
            for (int nt = 0; nt < 2; ++nt)
                acc[mt][nt] = (float4v)(0.0f);

        #pragma unroll
        for (int kt = 0; kt < 8; ++kt) {
            short8 a[4];
            #pragma unroll
            for (int mt = 0; mt < 4; ++mt) {
                int row = mt * 16 + l16;
                int cl  = (kt * 4 + quad) ^ (l16 & 7);
                a[mt] = *(const short8*)&sA[row * 256 + cl * 8];
            }
            #pragma unroll
            for (int mt = 0; mt < 4; ++mt)
                #pragma unroll
                for (int nt = 0; nt < 2; ++nt)
                    acc[mt][nt] = __builtin_amdgcn_mfma_f32_16x16x32_bf16(
                        a[mt], bw1[kt][nt], acc[mt][nt], 0, 0, 0);
        }

        // bias + relu -> sH bf16 (C/D layout: col=lane&15, row=quad*4+r)
        #pragma unroll
        for (int mt = 0; mt < 4; ++mt)
            #pragma unroll
            for (int nt = 0; nt < 2; ++nt)
                #pragma unroll
                for (int r = 0; r < 4; ++r) {
                    int m = mt * 16 + quad * 4 + r;
                    int n = nBase + nt * 16 + l16;
                    float h = fmaxf(acc[mt][nt][r] + b1v[nt], 0.0f);
                    sH[m * LDH + n] = f2bf(h);
                }

        BAR_LGKM;                    // sA free + sH ready (gather NOT drained)

        // ---- gather(t+G) in flight across the rest of the tile ----
        if (t + G < nTiles) gather(p);
        stageIdx(p ^ 1, t + 2 * G);

        // ---- GEMM2: OUT = H @ W2 + b2 ----
        float4v acc2[4][2];
        #pragma unroll
        for (int mt = 0; mt < 4; ++mt)
            #pragma unroll
            for (int nt = 0; nt < 2; ++nt)
                acc2[mt][nt] = (float4v)(0.0f);

        #pragma unroll
        for (int kt = 0; kt < 4; ++kt) {
            short8 a[4];
            #pragma unroll
            for (int mt = 0; mt < 4; ++mt)
                a[mt] = *(const short8*)&sH[(mt * 16 + l16) * LDH + kt * 32 + quad * 8];
            #pragma unroll
            for (int mt = 0; mt < 4; ++mt)
                #pragma unroll
                for (int nt = 0; nt < 2; ++nt)
                    acc2[mt][nt] = __builtin_amdgcn_mfma_f32_16x16x32_bf16(
                        a[mt], bw2[kt][nt], acc2[mt][nt], 0, 0, 0);
        }

        BAR_LGKM;                    // all waves done READING sH (slab overwrite safe)

        // ---- epilogue: per-wave fp32 slab in sH -> full-line NT float4 stores ----
        // slab: 32 rows x 34 floats per wave (1088 words), wave-local => no barriers
        {
            float* sHf = (float*)sH;
            const int slab = wave * 1088;
            #pragma unroll
            for (int ph = 0; ph < 2; ++ph) {      // row halves [0,32),[32,64)
                #pragma unroll
                for (int mh = 0; mh < 2; ++mh) {
                    int mt = 2 * ph + mh;
                    #pragma unroll
                    for (int nt = 0; nt < 2; ++nt)
                        #pragma unroll
                        for (int r = 0; r < 4; ++r) {
                            int row = mh * 16 + quad * 4 + r;   // 0..31
                            int c   = nt * 16 + l16;            // 0..31
                            sHf[slab + row * 34 + c] = acc2[mt][nt][r] + b2v[nt];
                        }
                }
                #pragma unroll
                for (int i = 0; i < 4; ++i) {
                    int f   = lane + 64 * i;      // float4 id in [0,256)
                    int row = f >> 3;             // 8 float4 per 32-float row
                    int c   = f & 7;
                    float4v v = *(const float4v*)&sHf[slab + row * 34 + c * 4];
                    long e = eBase + 32 * ph + row;
                    if (e < (long)E)
                        __builtin_nontemporal_store(
                            v, (float4v*)&out[e * 128 + nBase + c * 4]);
                }
            }
        }

        __syncthreads();             // vmcnt(0)+lgkm: gather landed, slab reads done
        p ^= 1;
    }
}

extern "C" void kernel_launch(void* const* d_in, const int* in_sizes, int n_in,
                              void* d_out, int out_size, void* d_ws, size_t ws_size,
                              hipStream_t stream) {
    const float* x  = (const float*)d_in[0];
    const int*   ei = (const int*)d_in[1];
    const float* W1 = (const float*)d_in[2];
    const float* b1 = (const float*)d_in[3];
    const float* W2 = (const float*)d_in[4];
    const float* b2 = (const float*)d_in[5];
    float* out = (float*)d_out;
    short* x16 = (short*)d_ws;                   // bf16 copy of x (12.8 MB)

    long n8 = (long)in_sizes[0] / 8;             // node floats / 8
    int cgrid = (int)((n8 + 255) / 256);
    cvt_x_kernel<<<cgrid, 256, 0, stream>>>(x, x16, n8);

    int E = in_sizes[1] / 2;                     // edge_index is [2, E]
    int nTiles = (E + E_TILE - 1) / E_TILE;      // 9375
    int grid = nTiles < PGRID ? nTiles : PGRID;
    edge_mlp_kernel<<<grid, 256, 0, stream>>>(x16, ei, W1, b1, W2, b2, out, E, nTiles);
}

// Round 3
// 437.637 us; speedup vs baseline: 1.0827x; 1.0827x over previous
//
#include <hip/hip_runtime.h>

typedef __attribute__((ext_vector_type(8))) short  short8;   // 8 x bf16 bits
typedef __attribute__((ext_vector_type(4))) float  float4v;
typedef __attribute__((ext_vector_type(4))) int    int4v;

#define E_TILE 64
#define PGRID  512   // persistent grid: 2 blocks/CU x 256 CU

// lgkm-only barrier: LDS drained, vmcnt (gathers/stores) stays in flight
#define BAR_LGKM asm volatile("s_waitcnt lgkmcnt(0)\n\ts_barrier" ::: "memory")
// tile-end: drain the 8 gathers (oldest), leave the 8 NT stores in flight
#define BAR_VM8  asm volatile("s_waitcnt vmcnt(8) lgkmcnt(0)\n\ts_barrier" ::: "memory")

// fp32 -> bf16 bits, round-to-nearest-even (weight prologue + H)
__device__ __forceinline__ short f2bf(float f) {
    union { float f; unsigned u; } v; v.f = f;
    unsigned r = (v.u + 0x7FFFu + ((v.u >> 16) & 1u)) >> 16;
    return (short)r;
}

// ---- pre-pass: x fp32 -> bf16 once (NT stores -> L3, don't churn L2) ----
__global__ __launch_bounds__(256)
void cvt_x_kernel(const float* __restrict__ x, short* __restrict__ x16, long n8) {
    long i = (long)blockIdx.x * 256 + threadIdx.x;   // units of 8 floats
    if (i >= n8) return;
    const float4v* p = (const float4v*)(x + i * 8);
    float4v a = p[0], b = p[1];
    unsigned r0, r1, r2, r3;
    asm("v_cvt_pk_bf16_f32 %0, %1, %2" : "=v"(r0) : "v"(a.x), "v"(a.y));
    asm("v_cvt_pk_bf16_f32 %0, %1, %2" : "=v"(r1) : "v"(a.z), "v"(a.w));
    asm("v_cvt_pk_bf16_f32 %0, %1, %2" : "=v"(r2) : "v"(b.x), "v"(b.y));
    asm("v_cvt_pk_bf16_f32 %0, %1, %2" : "=v"(r3) : "v"(b.z), "v"(b.w));
    int4v o; o.x = (int)r0; o.y = (int)r1; o.z = (int)r2; o.w = (int)r3;
    __builtin_nontemporal_store(o, (int4v*)(x16 + i * 8));
}

__global__ __launch_bounds__(256, 2)
void edge_mlp_kernel(const short* __restrict__ x16,
                     const int*   __restrict__ ei,
                     const float* __restrict__ W1,
                     const float* __restrict__ b1,
                     const float* __restrict__ W2,
                     const float* __restrict__ b2,
                     float*       __restrict__ out,
                     int E, int nTiles) {
    // Two DISTINCT LDS objects: LLVM proves gather(nxt) never aliases reads(cur)
    __shared__ short sA0[E_TILE * 256];       // 32 KiB
    __shared__ short sA1[E_TILE * 256];       // 32 KiB
    __shared__ int   sIdx[2][2 * E_TILE];     // 1 KiB  -> 65 KiB total, 2 blocks/CU

    const int tid  = threadIdx.x;
    const int wave = tid >> 6;
    const int lane = tid & 63;
    const int quad = lane >> 4;
    const int l16  = lane & 15;
    const int nBase = wave * 32;              // wave owns N-slice [nBase, nBase+32)
    const int G = gridDim.x;

    // ---- persistent weight preload (once per block) ----
    short8 bw1[8][2];   // K1=256: 8 k-steps; 2 n-tiles
    short8 bw2[4][2];   // K2=128: 4 k-steps
    #pragma unroll
    for (int kt = 0; kt < 8; ++kt)
        #pragma unroll
        for (int nt = 0; nt < 2; ++nt) {
            short8 f;
            #pragma unroll
            for (int j = 0; j < 8; ++j)
                f[j] = f2bf(W1[(kt * 32 + quad * 8 + j) * 128 + nBase + nt * 16 + l16]);
            bw1[kt][nt] = f;
        }
    #pragma unroll
    for (int kt = 0; kt < 4; ++kt)
        #pragma unroll
        for (int nt = 0; nt < 2; ++nt) {
            short8 f;
            #pragma unroll
            for (int j = 0; j < 8; ++j)
                f[j] = f2bf(W2[(kt * 32 + quad * 8 + j) * 128 + nBase + nt * 16 + l16]);
            bw2[kt][nt] = f;
        }
    float b1v[2], b2v[2];
    #pragma unroll
    for (int nt = 0; nt < 2; ++nt) {
        b1v[nt] = b1[nBase + nt * 16 + l16];
        b2v[nt] = b2[nBase + nt * 16 + l16];
    }

    auto stageIdx = [&](int b, int t) {
        if (tid < E_TILE) {
            int s = 0, d = 0;
            if (t < nTiles) {
                long eg = (long)t * E_TILE + tid;
                if (eg < (long)E) { s = ei[eg]; d = ei[(long)E + eg]; }
            }
            sIdx[b][tid] = s;
            sIdx[b][E_TILE + tid] = d;
        }
    };

    // gather tile into dstA: 2048 x 16B global_load_lds, linear LDS dest,
    // XOR-swizzled global source chunk (c = cl ^ (row&7))
    auto gather = [&](auto& dstA, int b) {
        #pragma unroll
        for (int r = 0; r < 8; ++r) {
            int lin = tid + 256 * r;              // chunk id [0,2048)
            int row = lin >> 5;                   // edge row (32 chunks/row)
            int cl  = lin & 31;
            int c   = cl ^ (row & 7);             // bit4 preserved: src/dst split keeps
            int node = (c < 16) ? sIdx[b][row] : sIdx[b][E_TILE + row];
            const short* gp = x16 + (long)node * 128 + (c & 15) * 8;
            __builtin_amdgcn_global_load_lds(
                (const __attribute__((address_space(1))) void*)gp,
                (__attribute__((address_space(3))) void*)&dstA[lin * 8],
                16, 0, 0);
        }
    };

    // ---- one tile: compute curA, prefetch t+G into nxtA (full-tile shadow) ----
    auto tile_body = [&](auto& curA, auto& nxtA, int idxR, int idxW, int t) {
        const long eBase = (long)t * E_TILE;

        // stage idx(t+2G) FIRST (its vmcnt wait retires before gathers, in-order),
        // then launch next tile's gather; pin order with a sched fence.
        stageIdx(idxW, t + 2 * G);
        const bool hasNext = (t + G < nTiles);
        if (hasNext) gather(nxtA, idxR);
        __builtin_amdgcn_sched_barrier(0);

        // ---- GEMM1: H = relu(A @ W1 + b1) ----
        float4v acc[4][2];
        #pragma unroll
        for (int mt = 0; mt < 4; ++mt)
            #pragma unroll
            for (int nt = 0; nt < 2; ++nt)
                acc[mt][nt] = (float4v)(0.0f);

        __builtin_amdgcn_s_setprio(1);
        #pragma unroll
        for (int kt = 0; kt < 8; ++kt) {
            short8 a[4];
            #pragma unroll
            for (int mt = 0; mt < 4; ++mt) {
                int row = mt * 16 + l16;
                int cl  = (kt * 4 + quad) ^ (l16 & 7);
                a[mt] = *(const short8*)&curA[row * 256 + cl * 8];
            }
            #pragma unroll
            for (int mt = 0; mt < 4; ++mt)
                #pragma unroll
                for (int nt = 0; nt < 2; ++nt)
                    acc[mt][nt] = __builtin_amdgcn_mfma_f32_16x16x32_bf16(
                        a[mt], bw1[kt][nt], acc[mt][nt], 0, 0, 0);
        }
        __builtin_amdgcn_s_setprio(0);

        BAR_LGKM;   // ALL waves' GEMM1 reads of curA done -> curA reusable

        // ---- H (bf16, XOR-swizzled 8-chunk) into curA[0:8192] shorts ----
        // phys = m*128 + ((hc ^ (m&7))<<3) + (n&7), hc = n>>3
        #pragma unroll
        for (int mt = 0; mt < 4; ++mt)
            #pragma unroll
            for (int nt = 0; nt < 2; ++nt) {
                int hcb = wave * 4 + nt * 2 + (l16 >> 3);
                #pragma unroll
                for (int r = 0; r < 4; ++r) {
                    int m = mt * 16 + quad * 4 + r;
                    float h = fmaxf(acc[mt][nt][r] + b1v[nt], 0.0f);
                    curA[m * 128 + ((hcb ^ (m & 7)) << 3) + (l16 & 7)] = f2bf(h);
                }
            }

        BAR_LGKM;   // H visible to all waves

        // ---- GEMM2: OUT = H @ W2 + b2 ----
        float4v acc2[4][2];
        #pragma unroll
        for (int mt = 0; mt < 4; ++mt)
            #pragma unroll
            for (int nt = 0; nt < 2; ++nt)
                acc2[mt][nt] = (float4v)(0.0f);

        __builtin_amdgcn_s_setprio(1);
        #pragma unroll
        for (int kt = 0; kt < 4; ++kt) {
            short8 a[4];
            #pragma unroll
            for (int mt = 0; mt < 4; ++mt) {
                int m = mt * 16 + l16;
                int hc = kt * 4 + quad;
                a[mt] = *(const short8*)&curA[m * 128 + ((hc ^ (l16 & 7)) << 3)];
            }
            #pragma unroll
            for (int mt = 0; mt < 4; ++mt)
                #pragma unroll
                for (int nt = 0; nt < 2; ++nt)
                    acc2[mt][nt] = __builtin_amdgcn_mfma_f32_16x16x32_bf16(
                        a[mt], bw2[kt][nt], acc2[mt][nt], 0, 0, 0);
        }
        __builtin_amdgcn_s_setprio(0);

        // ---- epilogue: per-wave fp32 slab in curA[16K:32K] (wave-local, no barrier;
        // disjoint from H region other waves may still be reading) ----
        float* slab = (float*)(&curA[0]) + 4096 + wave * 1024;  // 32 rows x 32 words
        #pragma unroll
        for (int ph = 0; ph < 2; ++ph) {
            #pragma unroll
            for (int mh = 0; mh < 2; ++mh)
                #pragma unroll
                for (int nt = 0; nt < 2; ++nt) {
                    int c4 = nt * 4 + (l16 >> 2);
                    #pragma unroll
                    for (int r = 0; r < 4; ++r) {
                        int row = mh * 16 + quad * 4 + r;
                        slab[row * 32 + ((c4 ^ (row & 7)) << 2) + (l16 & 3)] =
                            acc2[2 * ph + mh][nt][r] + b2v[nt];
                    }
                }
            #pragma unroll
            for (int i = 0; i < 4; ++i) {
                int f   = lane + 64 * i;          // [0,256)
                int row = f >> 3;
                int c4  = f & 7;
                float4v v = *(const float4v*)&slab[row * 32 + ((c4 ^ (row & 7)) << 2)];
                long e = eBase + 32 * ph + row;
                if (e < (long)E)
                    __builtin_nontemporal_store(
                        v, (float4v*)&out[e * 128 + nBase + c4 * 4]);
            }
        }

        BAR_VM8;    // drain 8 gathers (nxtA complete for everyone); stores fly on
    };

    // ---- prologue ----
    const int t0 = blockIdx.x;
    if (t0 >= nTiles) return;
    stageIdx(0, t0);
    stageIdx(1, t0 + G);
    __syncthreads();                 // sIdx visible
    gather(sA0, 0);
    __syncthreads();                 // drain prologue gather: sA0 ready

    // ---- 2-tile-unrolled persistent loop (static buffer roles) ----
    int t = t0;
    while (t < nTiles) {
        tile_body(sA0, sA1, 1, 0, t);        // compute sA0, prefetch t+G -> sA1
        t += G;
        if (t >= nTiles) break;
        tile_body(sA1, sA0, 0, 1, t);        // compute sA1, prefetch t+G -> sA0
        t += G;
    }
}

extern "C" void kernel_launch(void* const* d_in, const int* in_sizes, int n_in,
                              void* d_out, int out_size, void* d_ws, size_t ws_size,
                              hipStream_t stream) {
    const float* x  = (const float*)d_in[0];
    const int*   ei = (const int*)d_in[1];
    const float* W1 = (const float*)d_in[2];
    const float* b1 = (const float*)d_in[3];
    const float* W2 = (const float*)d_in[4];
    const float* b2 = (const float*)d_in[5];
    float* out = (float*)d_out;
    short* x16 = (short*)d_ws;                   // bf16 copy of x (12.8 MB)

    long n8 = (long)in_sizes[0] / 8;
    int cgrid = (int)((n8 + 255) / 256);
    cvt_x_kernel<<<cgrid, 256, 0, stream>>>(x, x16, n8);

    int E = in_sizes[1] / 2;                     // edge_index is [2, E]
    int nTiles = (E + E_TILE - 1) / E_TILE;      // 9375
    int grid = nTiles < PGRID ? nTiles : PGRID;
    edge_mlp_kernel<<<grid, 256, 0, stream>>>(x16, ei, W1, b1, W2, b2, out, E, nTiles);
}